// Round 7
// baseline (112.103 us; speedup 1.0000x reference)
//
#include <hip/hip_runtime.h>
#include <math.h>

#define N_NODES 4096
#define F_DIM 256
#define KEEP 2048
#define B_SZ 4

typedef float v4f __attribute__((ext_vector_type(4)));
typedef int   v4i __attribute__((ext_vector_type(4)));

// ---- exact IEEE f64 -> f32 (RNE) in integer space: immune to f32 denorm-flush modes ----
__device__ inline unsigned f64_to_f32_bits_rne(double x) {
    if (!(x > 0.0)) return 0u;                         // exact zero (never negative/NaN here)
    if (x >= 0x1p-126) {                               // normal f32 result
        unsigned long long xb = __double_as_longlong(x);
        int E = (int)((xb >> 52) & 0x7FFull) - 1023;
        unsigned long long mant = xb & 0xFFFFFFFFFFFFFull;
        unsigned m23 = (unsigned)(mant >> 29);
        unsigned long long rem = mant & ((1ull << 29) - 1ull);
        const unsigned long long half = 1ull << 28;
        if (rem > half || (rem == half && (m23 & 1u))) {
            m23++;
            if (m23 == (1u << 23)) { m23 = 0u; E++; }
        }
        return ((unsigned)(E + 127) << 23) | m23;
    } else {                                           // subnormal f32 result
        double r = x * 0x1p149;                        // exact scale
        double ri = rint(r);                           // RNE to integer quanta
        return (unsigned)ri;                           // k quanta of 2^-149
    }
}

__device__ inline double f32_bits_to_f64(unsigned b) {
    int e = (int)((b >> 23) & 0xFFu);
    unsigned m = b & 0x7FFFFFu;
    if (e == 0) return (double)m * 0x1p-149;
    return ldexp((double)(m | 0x800000u), e - 150);
}

// K1: xw[b*N+m] = dot(Xs[b,m,:], w)  -- f64 accumulate, one wave per row
__global__ __launch_bounds__(256) void k_xw(const float* __restrict__ Xs,
                                            const float* __restrict__ w,
                                            double* __restrict__ xw) {
    int wave = threadIdx.x >> 6;
    int lane = threadIdx.x & 63;
    int row  = blockIdx.x * 4 + wave;                 // b*N + m
    const float4* xr = (const float4*)(Xs + (size_t)row * F_DIM);
    const float4* wr = (const float4*)w;
    float4 x  = xr[lane];
    float4 ww = wr[lane];
    double s = (double)x.x*ww.x + (double)x.y*ww.y + (double)x.z*ww.z + (double)x.w*ww.w;
    #pragma unroll
    for (int off = 32; off > 0; off >>= 1) s += __shfl_xor(s, off, 64);
    if (lane == 0) xw[row] = s;
}

// K2: logits[row] = dot(A[row,:], xw[b,:])  -- f64 accumulate, one block per row
__global__ __launch_bounds__(256) void k_logits(const float* __restrict__ A,
                                                const double* __restrict__ xw,
                                                double* __restrict__ logits) {
    int row = blockIdx.x;            // b*N + n
    int b   = row >> 12;
    const float4*  ar = (const float4*)(A + (size_t)row * N_NODES);
    const double*  xr = xw + b * N_NODES;
    int t = threadIdx.x;
    double s = 0.0;
    #pragma unroll
    for (int it = 0; it < 4; ++it) {
        int i4 = it * 256 + t;
        float4 a = ar[i4];
        const double* xp = xr + i4 * 4;
        s += a.x*xp[0] + a.y*xp[1] + a.z*xp[2] + a.w*xp[3];
    }
    #pragma unroll
    for (int off = 32; off > 0; off >>= 1) s += __shfl_xor(s, off, 64);
    __shared__ double red[4];
    if ((t & 63) == 0) red[t >> 6] = s;
    __syncthreads();
    if (t == 0) logits[row] = red[0] + red[1] + red[2] + red[3];
}

// K3: f32 softmax emulation (numpy SIMD expf semantics) + top-K by O(N) rank
// construction. Total order: (score desc, index asc). Unchanged from round 5.
__global__ __launch_bounds__(1024) void k_topk(const double* __restrict__ logits,
                                               int* __restrict__ keep_idx,
                                               unsigned* __restrict__ keep_val_bits) {
    int b = blockIdx.x;
    int t = threadIdx.x;
    int wave = t >> 6, lane = t & 63;
    __shared__ unsigned qb[N_NODES];   // logit bits -> exp bits -> score bits
    __shared__ int nz[N_NODES];        // compacted nonzero indices
    __shared__ double wredd[16];
    __shared__ int wredi[16];
    const double* L = logits + b * N_NODES;

    // pass 1: f32 logits + max
    float lmax = -INFINITY;
    #pragma unroll
    for (int k = 0; k < 4; ++k) {
        int i = t + k * 1024;
        float v = (float)L[i];
        qb[i] = __float_as_uint(v);
        lmax = fmaxf(lmax, v);
    }
    #pragma unroll
    for (int off = 32; off > 0; off >>= 1) lmax = fmaxf(lmax, __shfl_xor(lmax, off, 64));
    if (lane == 0) wredd[wave] = (double)lmax;
    __syncthreads();
    float m = (float)wredd[0];
    #pragma unroll
    for (int i = 1; i < 16; ++i) m = fmaxf(m, (float)wredd[i]);
    __syncthreads();

    // pass 2: e32 = round_f32(exp(d)); numpy semantics: flush below FLT_MIN to 0
    double lsum = 0.0;
    #pragma unroll
    for (int k = 0; k < 4; ++k) {
        int i = t + k * 1024;
        float d = __uint_as_float(qb[i]) - m;
        unsigned ebits = 0u;
        if (d >= -87.3365402f) {                        // numpy expf xmin cutoff
            ebits = f64_to_f32_bits_rne(exp((double)d));
            if (ebits < 0x00800000u) ebits = 0u;        // no subnormal exp outputs
        }
        qb[i] = ebits;
        lsum += f32_bits_to_f64(ebits);
    }
    #pragma unroll
    for (int off = 32; off > 0; off >>= 1) lsum += __shfl_xor(lsum, off, 64);
    if (lane == 0) wredd[wave] = lsum;
    __syncthreads();
    double S64 = 0.0;
    #pragma unroll
    for (int i = 0; i < 16; ++i) S64 += wredd[i];
    double Sv = f32_bits_to_f64(f64_to_f32_bits_rne(S64));

    // pass 3: score bits = round_f32(e32 / S32)
    #pragma unroll
    for (int k = 0; k < 4; ++k) {
        int i = t + k * 1024;
        qb[i] = f64_to_f32_bits_rne(f32_bits_to_f64(qb[i]) / Sv);
    }
    __syncthreads();

    // scan over zero-flags; thread owns 4 consecutive elements
    int i0 = 4 * t;
    unsigned s0 = qb[i0], s1 = qb[i0+1], s2 = qb[i0+2], s3 = qb[i0+3];
    int f0 = (s0 == 0u), f1 = (s1 == 0u), f2 = (s2 == 0u), f3 = (s3 == 0u);
    int mysum = f0 + f1 + f2 + f3;
    int inc = mysum;
    #pragma unroll
    for (int off = 1; off < 64; off <<= 1) {
        int u = __shfl_up(inc, off, 64);
        if (lane >= off) inc += u;
    }
    if (lane == 63) wredi[wave] = inc;
    __syncthreads();
    int waveoff = 0, Z = 0;
    for (int j = 0; j < 16; ++j) { int v = wredi[j]; Z += v; if (j < wave) waveoff += v; }
    int C = N_NODES - Z;
    int ez = waveoff + inc - mysum;       // #zeros before element i0

    // emit zeros directly; compact nonzeros into nz[]
    int fl4[4] = {f0, f1, f2, f3};
    #pragma unroll
    for (int k = 0; k < 4; ++k) {
        int i = i0 + k;
        if (fl4[k]) {
            int r = C + ez;
            if (r < KEEP) { keep_idx[b*KEEP + r] = i; keep_val_bits[b*KEEP + r] = 0u; }
            ez++;
        } else {
            nz[i - ez] = i;               // compact pos = i - (#zeros < i)
        }
    }
    __syncthreads();

    // rank nonzeros by brute-force comparison among the C of them
    for (int p = t; p < C; p += 1024) {
        int i = nz[p];
        unsigned sv = qb[i];
        int rank = 0;
        for (int p2 = 0; p2 < C; ++p2) {
            int j = nz[p2];
            unsigned sj = qb[j];
            rank += (sj > sv) || (sj == sv && j < i);
        }
        if (rank < KEEP) { keep_idx[b*KEEP + rank] = i; keep_val_bits[b*KEEP + rank] = sv; }
    }
}

// K4: Xs_out[b,k,:] = Xs[b, idx[b,k], :]  -- cached loads, nt stores
__global__ __launch_bounds__(256) void k_gatherX(const float* __restrict__ Xs,
                                                 const int* __restrict__ keep_idx,
                                                 float* __restrict__ Xout) {
    int wave = threadIdx.x >> 6;
    int lane = threadIdx.x & 63;
    int r = blockIdx.x * 4 + wave;   // b*KEEP + k
    int b = r >> 11;
    int src = keep_idx[r];
    const v4f* in  = (const v4f*)(Xs + ((size_t)(b * N_NODES + src)) * F_DIM);
    v4f*       out = (v4f*)(Xout + (size_t)r * F_DIM);
    __builtin_nontemporal_store(in[lane], out + lane);
}

// K5: As_out[b,i,j] = As[b, idx[b,i], idx[b,j]]
// Cached row loads (harvest L3 residency from k_logits' As stream);
// LDS stage; vectorized idx loads; non-temporal vectorized stores.
__global__ __launch_bounds__(256) void k_gatherA(const float* __restrict__ A,
                                                 const int* __restrict__ keep_idx,
                                                 float* __restrict__ Aout) {
    int r = blockIdx.x;              // b*KEEP + i
    int b = r >> 11;
    int src = keep_idx[r];
    __shared__ float row[N_NODES];   // 16 KB
    const v4f* in = (const v4f*)(A + ((size_t)(b * N_NODES + src)) * N_NODES);
    v4f* rowv = (v4f*)row;
    int t = threadIdx.x;
    #pragma unroll
    for (int it = 0; it < 4; ++it) rowv[it * 256 + t] = in[it * 256 + t];
    __syncthreads();
    const int* idx = keep_idx + b * KEEP;
    float* outp = Aout + (size_t)r * KEEP;
    int j0 = 8 * t;                  // 8 consecutive output columns per thread
    v4i ia = *(const v4i*)(idx + j0);
    v4i ib = *(const v4i*)(idx + j0 + 4);
    v4f oa, ob;
    oa.x = row[ia.x]; oa.y = row[ia.y]; oa.z = row[ia.z]; oa.w = row[ia.w];
    ob.x = row[ib.x]; ob.y = row[ib.y]; ob.z = row[ib.z]; ob.w = row[ib.w];
    __builtin_nontemporal_store(oa, (v4f*)(outp + j0));
    __builtin_nontemporal_store(ob, (v4f*)(outp + j0 + 4));
}

extern "C" void kernel_launch(void* const* d_in, const int* in_sizes, int n_in,
                              void* d_out, int out_size, void* d_ws, size_t ws_size,
                              hipStream_t stream) {
    const float* Xs = (const float*)d_in[0];   // [4,4096,256]
    const float* As = (const float*)d_in[1];   // [4,4096,4096]
    const float* w  = (const float*)d_in[2];   // [256,1]

    float* out  = (float*)d_out;
    float* Xout = out;                                   // 4*2048*256
    float* Aout = out + (size_t)B_SZ * KEEP * F_DIM;     // 4*2048*2048
    unsigned* KV = (unsigned*)(Aout + (size_t)B_SZ * KEEP * KEEP);  // raw f32 bits

    char* ws = (char*)d_ws;
    double* xw       = (double*)ws;              // 128 KB
    double* logits   = (double*)(ws + 131072);   // 128 KB
    int*    keep_idx = (int*)(ws + 262144);      // 32 KB

    k_xw     <<<B_SZ * N_NODES / 4, 256, 0, stream>>>(Xs, w, xw);
    k_logits <<<B_SZ * N_NODES,     256, 0, stream>>>(As, xw, logits);
    k_topk   <<<B_SZ,              1024, 0, stream>>>(logits, keep_idx, KV);
    k_gatherX<<<B_SZ * KEEP / 4,    256, 0, stream>>>(Xs, keep_idx, Xout);
    k_gatherA<<<B_SZ * KEEP,        256, 0, stream>>>(As, keep_idx, Aout);
}

// Round 8
// 90.339 us; speedup vs baseline: 1.2409x; 1.2409x over previous
//
#include <hip/hip_runtime.h>
#include <math.h>

#define N_NODES 4096
#define F_DIM 256
#define KEEP 2048
#define B_SZ 4
#define LROWS 4

// ---- exact IEEE f64 -> f32 (RNE) in integer space: immune to f32 denorm-flush modes ----
__device__ inline unsigned f64_to_f32_bits_rne(double x) {
    if (!(x > 0.0)) return 0u;                         // exact zero (never negative/NaN here)
    if (x >= 0x1p-126) {                               // normal f32 result
        unsigned long long xb = __double_as_longlong(x);
        int E = (int)((xb >> 52) & 0x7FFull) - 1023;
        unsigned long long mant = xb & 0xFFFFFFFFFFFFFull;
        unsigned m23 = (unsigned)(mant >> 29);
        unsigned long long rem = mant & ((1ull << 29) - 1ull);
        const unsigned long long half = 1ull << 28;
        if (rem > half || (rem == half && (m23 & 1u))) {
            m23++;
            if (m23 == (1u << 23)) { m23 = 0u; E++; }
        }
        return ((unsigned)(E + 127) << 23) | m23;
    } else {                                           // subnormal f32 result
        double r = x * 0x1p149;                        // exact scale
        double ri = rint(r);                           // RNE to integer quanta
        return (unsigned)ri;                           // k quanta of 2^-149
    }
}

__device__ inline double f32_bits_to_f64(unsigned b) {
    int e = (int)((b >> 23) & 0xFFu);
    unsigned m = b & 0x7FFFFFu;
    if (e == 0) return (double)m * 0x1p-149;
    return ldexp((double)(m | 0x800000u), e - 150);
}

// K1: xw[b*N+m] = dot(Xs[b,m,:], w)  -- f64 accumulate, one wave per row
__global__ __launch_bounds__(256) void k_xw(const float* __restrict__ Xs,
                                            const float* __restrict__ w,
                                            double* __restrict__ xw) {
    int wave = threadIdx.x >> 6;
    int lane = threadIdx.x & 63;
    int row  = blockIdx.x * 4 + wave;                 // b*N + m
    const float4* xr = (const float4*)(Xs + (size_t)row * F_DIM);
    const float4* wr = (const float4*)w;
    float4 x  = xr[lane];
    float4 ww = wr[lane];
    double s = (double)x.x*ww.x + (double)x.y*ww.y + (double)x.z*ww.z + (double)x.w*ww.w;
    #pragma unroll
    for (int off = 32; off > 0; off >>= 1) s += __shfl_xor(s, off, 64);
    if (lane == 0) xw[row] = s;
}

// K2: logits for 4 consecutive rows per block -- one xw read amortized over 4
// A-rows. Per-row accumulation & reduction order bitwise identical to before.
__global__ __launch_bounds__(256) void k_logits(const float* __restrict__ A,
                                                const double* __restrict__ xw,
                                                double* __restrict__ logits) {
    int rb = blockIdx.x * LROWS;     // first row (b*N + n); all 4 rows same batch
    int b  = rb >> 12;
    int t  = threadIdx.x;
    const float4*  ar = (const float4*)(A + (size_t)rb * N_NODES);
    const double*  xr = xw + b * N_NODES;
    double s0 = 0.0, s1 = 0.0, s2 = 0.0, s3 = 0.0;
    #pragma unroll
    for (int it = 0; it < 4; ++it) {
        int i4 = it * 256 + t;       // float4 chunk 0..1023
        const double* xp = xr + i4 * 4;
        double x0 = xp[0], x1 = xp[1], x2 = xp[2], x3 = xp[3];
        float4 a0 = ar[i4];
        float4 a1 = ar[1024 + i4];
        float4 a2 = ar[2048 + i4];
        float4 a3 = ar[3072 + i4];
        s0 += a0.x*x0 + a0.y*x1 + a0.z*x2 + a0.w*x3;
        s1 += a1.x*x0 + a1.y*x1 + a1.z*x2 + a1.w*x3;
        s2 += a2.x*x0 + a2.y*x1 + a2.z*x2 + a2.w*x3;
        s3 += a3.x*x0 + a3.y*x1 + a3.z*x2 + a3.w*x3;
    }
    #pragma unroll
    for (int off = 32; off > 0; off >>= 1) {
        s0 += __shfl_xor(s0, off, 64);
        s1 += __shfl_xor(s1, off, 64);
        s2 += __shfl_xor(s2, off, 64);
        s3 += __shfl_xor(s3, off, 64);
    }
    __shared__ double red[LROWS][4];
    int wave = t >> 6;
    if ((t & 63) == 0) {
        red[0][wave] = s0; red[1][wave] = s1; red[2][wave] = s2; red[3][wave] = s3;
    }
    __syncthreads();
    if (t < LROWS)
        logits[rb + t] = red[t][0] + red[t][1] + red[t][2] + red[t][3];
}

// K3: f32 softmax emulation (numpy SIMD expf semantics) + top-K by O(N) rank
// construction. Total order: (score desc, index asc). Unchanged (bit-frozen).
__global__ __launch_bounds__(1024) void k_topk(const double* __restrict__ logits,
                                               int* __restrict__ keep_idx,
                                               unsigned* __restrict__ keep_val_bits) {
    int b = blockIdx.x;
    int t = threadIdx.x;
    int wave = t >> 6, lane = t & 63;
    __shared__ unsigned qb[N_NODES];   // logit bits -> exp bits -> score bits
    __shared__ int nz[N_NODES];        // compacted nonzero indices
    __shared__ double wredd[16];
    __shared__ int wredi[16];
    const double* L = logits + b * N_NODES;

    // pass 1: f32 logits + max
    float lmax = -INFINITY;
    #pragma unroll
    for (int k = 0; k < 4; ++k) {
        int i = t + k * 1024;
        float v = (float)L[i];
        qb[i] = __float_as_uint(v);
        lmax = fmaxf(lmax, v);
    }
    #pragma unroll
    for (int off = 32; off > 0; off >>= 1) lmax = fmaxf(lmax, __shfl_xor(lmax, off, 64));
    if (lane == 0) wredd[wave] = (double)lmax;
    __syncthreads();
    float m = (float)wredd[0];
    #pragma unroll
    for (int i = 1; i < 16; ++i) m = fmaxf(m, (float)wredd[i]);
    __syncthreads();

    // pass 2: e32 = round_f32(exp(d)); numpy semantics: flush below FLT_MIN to 0
    double lsum = 0.0;
    #pragma unroll
    for (int k = 0; k < 4; ++k) {
        int i = t + k * 1024;
        float d = __uint_as_float(qb[i]) - m;
        unsigned ebits = 0u;
        if (d >= -87.3365402f) {                        // numpy expf xmin cutoff
            ebits = f64_to_f32_bits_rne(exp((double)d));
            if (ebits < 0x00800000u) ebits = 0u;        // no subnormal exp outputs
        }
        qb[i] = ebits;
        lsum += f32_bits_to_f64(ebits);
    }
    #pragma unroll
    for (int off = 32; off > 0; off >>= 1) lsum += __shfl_xor(lsum, off, 64);
    if (lane == 0) wredd[wave] = lsum;
    __syncthreads();
    double S64 = 0.0;
    #pragma unroll
    for (int i = 0; i < 16; ++i) S64 += wredd[i];
    double Sv = f32_bits_to_f64(f64_to_f32_bits_rne(S64));

    // pass 3: score bits = round_f32(e32 / S32)
    #pragma unroll
    for (int k = 0; k < 4; ++k) {
        int i = t + k * 1024;
        qb[i] = f64_to_f32_bits_rne(f32_bits_to_f64(qb[i]) / Sv);
    }
    __syncthreads();

    // scan over zero-flags; thread owns 4 consecutive elements
    int i0 = 4 * t;
    unsigned s0 = qb[i0], s1 = qb[i0+1], s2 = qb[i0+2], s3 = qb[i0+3];
    int f0 = (s0 == 0u), f1 = (s1 == 0u), f2 = (s2 == 0u), f3 = (s3 == 0u);
    int mysum = f0 + f1 + f2 + f3;
    int inc = mysum;
    #pragma unroll
    for (int off = 1; off < 64; off <<= 1) {
        int u = __shfl_up(inc, off, 64);
        if (lane >= off) inc += u;
    }
    if (lane == 63) wredi[wave] = inc;
    __syncthreads();
    int waveoff = 0, Z = 0;
    for (int j = 0; j < 16; ++j) { int v = wredi[j]; Z += v; if (j < wave) waveoff += v; }
    int C = N_NODES - Z;
    int ez = waveoff + inc - mysum;       // #zeros before element i0

    // emit zeros directly; compact nonzeros into nz[]
    int fl4[4] = {f0, f1, f2, f3};
    #pragma unroll
    for (int k = 0; k < 4; ++k) {
        int i = i0 + k;
        if (fl4[k]) {
            int r = C + ez;
            if (r < KEEP) { keep_idx[b*KEEP + r] = i; keep_val_bits[b*KEEP + r] = 0u; }
            ez++;
        } else {
            nz[i - ez] = i;               // compact pos = i - (#zeros < i)
        }
    }
    __syncthreads();

    // rank nonzeros by brute-force comparison among the C of them
    for (int p = t; p < C; p += 1024) {
        int i = nz[p];
        unsigned sv = qb[i];
        int rank = 0;
        for (int p2 = 0; p2 < C; ++p2) {
            int j = nz[p2];
            unsigned sj = qb[j];
            rank += (sj > sv) || (sj == sv && j < i);
        }
        if (rank < KEEP) { keep_idx[b*KEEP + rank] = i; keep_val_bits[b*KEEP + rank] = sv; }
    }
}

// K4 (fused gather). Blocks [0, XBLKS): Xs_out rows (4/block, one per wave).
// Blocks [XBLKS, XBLKS+8192): As_out rows -- R5's conflict-free patterns:
// coalesced float4 row stage, then j=q*256+t scalar LDS gather (stride-2
// across lanes = 2-way bank aliasing = free). Cached loads and stores.
#define XBLKS (B_SZ * KEEP / 4)
__global__ __launch_bounds__(256) void k_gather(const float* __restrict__ Xs,
                                                const float* __restrict__ As,
                                                const int* __restrict__ keep_idx,
                                                float* __restrict__ Xout,
                                                float* __restrict__ Aout) {
    __shared__ float row[N_NODES];   // A-path only
    int t = threadIdx.x;
    if (blockIdx.x < XBLKS) {
        int wave = t >> 6, lane = t & 63;
        int r = blockIdx.x * 4 + wave;       // b*KEEP + k
        int b = r >> 11;
        int src = keep_idx[r];
        const float4* in  = (const float4*)(Xs + ((size_t)(b * N_NODES + src)) * F_DIM);
        float4*       out = (float4*)(Xout + (size_t)r * F_DIM);
        out[lane] = in[lane];
    } else {
        int r = blockIdx.x - XBLKS;          // b*KEEP + i
        int b = r >> 11;
        int src = keep_idx[r];
        const float4* in = (const float4*)(As + ((size_t)(b * N_NODES + src)) * N_NODES);
        float4* rowv = (float4*)row;
        #pragma unroll
        for (int it = 0; it < 4; ++it) rowv[it * 256 + t] = in[it * 256 + t];
        __syncthreads();
        const int* idx = keep_idx + b * KEEP;
        float* outp = Aout + (size_t)r * KEEP;
        #pragma unroll
        for (int q = 0; q < 8; ++q) {
            int j = q * 256 + t;
            outp[j] = row[idx[j]];
        }
    }
}

extern "C" void kernel_launch(void* const* d_in, const int* in_sizes, int n_in,
                              void* d_out, int out_size, void* d_ws, size_t ws_size,
                              hipStream_t stream) {
    const float* Xs = (const float*)d_in[0];   // [4,4096,256]
    const float* As = (const float*)d_in[1];   // [4,4096,4096]
    const float* w  = (const float*)d_in[2];   // [256,1]

    float* out  = (float*)d_out;
    float* Xout = out;                                   // 4*2048*256
    float* Aout = out + (size_t)B_SZ * KEEP * F_DIM;     // 4*2048*2048
    unsigned* KV = (unsigned*)(Aout + (size_t)B_SZ * KEEP * KEEP);  // raw f32 bits

    char* ws = (char*)d_ws;
    double* xw       = (double*)ws;              // 128 KB
    double* logits   = (double*)(ws + 131072);   // 128 KB
    int*    keep_idx = (int*)(ws + 262144);      // 32 KB

    k_xw     <<<B_SZ * N_NODES / 4,      256, 0, stream>>>(Xs, w, xw);
    k_logits <<<B_SZ * N_NODES / LROWS,  256, 0, stream>>>(As, xw, logits);
    k_topk   <<<B_SZ,                   1024, 0, stream>>>(logits, keep_idx, KV);
    k_gather <<<XBLKS + B_SZ * KEEP,     256, 0, stream>>>(Xs, As, keep_idx, Xout, Aout);
}

// Round 10
// 87.489 us; speedup vs baseline: 1.2813x; 1.0326x over previous
//
#include <hip/hip_runtime.h>
#include <math.h>

#define N_NODES 4096
#define F_DIM 256
#define KEEP 2048
#define B_SZ 4
#define LROWS 8

typedef float v4f __attribute__((ext_vector_type(4)));

// ---- exact IEEE f64 -> f32 (RNE) in integer space: immune to f32 denorm-flush modes ----
__device__ inline unsigned f64_to_f32_bits_rne(double x) {
    if (!(x > 0.0)) return 0u;                         // exact zero (never negative/NaN here)
    if (x >= 0x1p-126) {                               // normal f32 result
        unsigned long long xb = __double_as_longlong(x);
        int E = (int)((xb >> 52) & 0x7FFull) - 1023;
        unsigned long long mant = xb & 0xFFFFFFFFFFFFFull;
        unsigned m23 = (unsigned)(mant >> 29);
        unsigned long long rem = mant & ((1ull << 29) - 1ull);
        const unsigned long long half = 1ull << 28;
        if (rem > half || (rem == half && (m23 & 1u))) {
            m23++;
            if (m23 == (1u << 23)) { m23 = 0u; E++; }
        }
        return ((unsigned)(E + 127) << 23) | m23;
    } else {                                           // subnormal f32 result
        double r = x * 0x1p149;                        // exact scale
        double ri = rint(r);                           // RNE to integer quanta
        return (unsigned)ri;                           // k quanta of 2^-149
    }
}

__device__ inline double f32_bits_to_f64(unsigned b) {
    int e = (int)((b >> 23) & 0xFFu);
    unsigned m = b & 0x7FFFFFu;
    if (e == 0) return (double)m * 0x1p-149;
    return ldexp((double)(m | 0x800000u), e - 150);
}

// K1: xw[b*N+m] = dot(Xs[b,m,:], w)  -- f64 accumulate, one wave per row
__global__ __launch_bounds__(256) void k_xw(const float* __restrict__ Xs,
                                            const float* __restrict__ w,
                                            double* __restrict__ xw) {
    int wave = threadIdx.x >> 6;
    int lane = threadIdx.x & 63;
    int row  = blockIdx.x * 4 + wave;                 // b*N + m
    const float4* xr = (const float4*)(Xs + (size_t)row * F_DIM);
    const float4* wr = (const float4*)w;
    float4 x  = xr[lane];
    float4 ww = wr[lane];
    double s = (double)x.x*ww.x + (double)x.y*ww.y + (double)x.z*ww.z + (double)x.w*ww.w;
    #pragma unroll
    for (int off = 32; off > 0; off >>= 1) s += __shfl_xor(s, off, 64);
    if (lane == 0) xw[row] = s;
}

// K2: logits for 8 consecutive rows per block -- one xw read amortized over 8
// A-rows. Per-row accumulation & reduction order bitwise identical to before.
__global__ __launch_bounds__(256) void k_logits(const float* __restrict__ A,
                                                const double* __restrict__ xw,
                                                double* __restrict__ logits) {
    int rb = blockIdx.x * LROWS;     // first row (b*N + n); all 8 rows same batch
    int b  = rb >> 12;
    int t  = threadIdx.x;
    const float4*  ar = (const float4*)(A + (size_t)rb * N_NODES);
    const double*  xr = xw + b * N_NODES;
    double s[LROWS];
    #pragma unroll
    for (int r = 0; r < LROWS; ++r) s[r] = 0.0;
    #pragma unroll
    for (int it = 0; it < 4; ++it) {
        int i4 = it * 256 + t;       // float4 chunk 0..1023
        const double* xp = xr + i4 * 4;
        double x0 = xp[0], x1 = xp[1], x2 = xp[2], x3 = xp[3];
        #pragma unroll
        for (int r = 0; r < LROWS; ++r) {
            float4 a = ar[r * 1024 + i4];
            s[r] += a.x*x0 + a.y*x1 + a.z*x2 + a.w*x3;
        }
    }
    #pragma unroll
    for (int r = 0; r < LROWS; ++r) {
        #pragma unroll
        for (int off = 32; off > 0; off >>= 1) s[r] += __shfl_xor(s[r], off, 64);
    }
    __shared__ double red[LROWS][4];
    int wave = t >> 6;
    if ((t & 63) == 0) {
        #pragma unroll
        for (int r = 0; r < LROWS; ++r) red[r][wave] = s[r];
    }
    __syncthreads();
    if (t < LROWS)
        logits[rb + t] = red[t][0] + red[t][1] + red[t][2] + red[t][3];
}

// K3: f32 softmax emulation (numpy SIMD expf semantics) + top-K by O(N) rank
// construction. Total order: (score desc, index asc). Unchanged (bit-frozen).
__global__ __launch_bounds__(1024) void k_topk(const double* __restrict__ logits,
                                               int* __restrict__ keep_idx,
                                               unsigned* __restrict__ keep_val_bits) {
    int b = blockIdx.x;
    int t = threadIdx.x;
    int wave = t >> 6, lane = t & 63;
    __shared__ unsigned qb[N_NODES];   // logit bits -> exp bits -> score bits
    __shared__ int nz[N_NODES];        // compacted nonzero indices
    __shared__ double wredd[16];
    __shared__ int wredi[16];
    const double* L = logits + b * N_NODES;

    // pass 1: f32 logits + max
    float lmax = -INFINITY;
    #pragma unroll
    for (int k = 0; k < 4; ++k) {
        int i = t + k * 1024;
        float v = (float)L[i];
        qb[i] = __float_as_uint(v);
        lmax = fmaxf(lmax, v);
    }
    #pragma unroll
    for (int off = 32; off > 0; off >>= 1) lmax = fmaxf(lmax, __shfl_xor(lmax, off, 64));
    if (lane == 0) wredd[wave] = (double)lmax;
    __syncthreads();
    float m = (float)wredd[0];
    #pragma unroll
    for (int i = 1; i < 16; ++i) m = fmaxf(m, (float)wredd[i]);
    __syncthreads();

    // pass 2: e32 = round_f32(exp(d)); numpy semantics: flush below FLT_MIN to 0
    double lsum = 0.0;
    #pragma unroll
    for (int k = 0; k < 4; ++k) {
        int i = t + k * 1024;
        float d = __uint_as_float(qb[i]) - m;
        unsigned ebits = 0u;
        if (d >= -87.3365402f) {                        // numpy expf xmin cutoff
            ebits = f64_to_f32_bits_rne(exp((double)d));
            if (ebits < 0x00800000u) ebits = 0u;        // no subnormal exp outputs
        }
        qb[i] = ebits;
        lsum += f32_bits_to_f64(ebits);
    }
    #pragma unroll
    for (int off = 32; off > 0; off >>= 1) lsum += __shfl_xor(lsum, off, 64);
    if (lane == 0) wredd[wave] = lsum;
    __syncthreads();
    double S64 = 0.0;
    #pragma unroll
    for (int i = 0; i < 16; ++i) S64 += wredd[i];
    double Sv = f32_bits_to_f64(f64_to_f32_bits_rne(S64));

    // pass 3: score bits = round_f32(e32 / S32)
    #pragma unroll
    for (int k = 0; k < 4; ++k) {
        int i = t + k * 1024;
        qb[i] = f64_to_f32_bits_rne(f32_bits_to_f64(qb[i]) / Sv);
    }
    __syncthreads();

    // scan over zero-flags; thread owns 4 consecutive elements
    int i0 = 4 * t;
    unsigned s0 = qb[i0], s1 = qb[i0+1], s2 = qb[i0+2], s3 = qb[i0+3];
    int f0 = (s0 == 0u), f1 = (s1 == 0u), f2 = (s2 == 0u), f3 = (s3 == 0u);
    int mysum = f0 + f1 + f2 + f3;
    int inc = mysum;
    #pragma unroll
    for (int off = 1; off < 64; off <<= 1) {
        int u = __shfl_up(inc, off, 64);
        if (lane >= off) inc += u;
    }
    if (lane == 63) wredi[wave] = inc;
    __syncthreads();
    int waveoff = 0, Z = 0;
    for (int j = 0; j < 16; ++j) { int v = wredi[j]; Z += v; if (j < wave) waveoff += v; }
    int C = N_NODES - Z;
    int ez = waveoff + inc - mysum;       // #zeros before element i0

    // emit zeros directly; compact nonzeros into nz[]
    int fl4[4] = {f0, f1, f2, f3};
    #pragma unroll
    for (int k = 0; k < 4; ++k) {
        int i = i0 + k;
        if (fl4[k]) {
            int r = C + ez;
            if (r < KEEP) { keep_idx[b*KEEP + r] = i; keep_val_bits[b*KEEP + r] = 0u; }
            ez++;
        } else {
            nz[i - ez] = i;               // compact pos = i - (#zeros < i)
        }
    }
    __syncthreads();

    // rank nonzeros by brute-force comparison among the C of them
    for (int p = t; p < C; p += 1024) {
        int i = nz[p];
        unsigned sv = qb[i];
        int rank = 0;
        for (int p2 = 0; p2 < C; ++p2) {
            int j = nz[p2];
            unsigned sj = qb[j];
            rank += (sj > sv) || (sj == sv && j < i);
        }
        if (rank < KEEP) { keep_idx[b*KEEP + rank] = i; keep_val_bits[b*KEEP + rank] = sv; }
    }
}

// K4 (fused gather). Blocks [0, XBLKS): Xs_out rows (4/block, one per wave).
// Blocks [XBLKS, XBLKS+8192): As_out rows -- conflict-free patterns:
// coalesced float4 row stage (CACHED loads: harvest As L3 residency from
// k_logits), then j=q*256+t scalar LDS gather (stride-2 = free 2-way).
// Stores NON-TEMPORAL (via ext_vector v4f / scalar float): don't let 75 MB
// of output writes evict As from L3.
#define XBLKS (B_SZ * KEEP / 4)
__global__ __launch_bounds__(256) void k_gather(const float* __restrict__ Xs,
                                                const float* __restrict__ As,
                                                const int* __restrict__ keep_idx,
                                                float* __restrict__ Xout,
                                                float* __restrict__ Aout) {
    __shared__ float row[N_NODES];   // A-path only
    int t = threadIdx.x;
    if (blockIdx.x < XBLKS) {
        int wave = t >> 6, lane = t & 63;
        int r = blockIdx.x * 4 + wave;       // b*KEEP + k
        int b = r >> 11;
        int src = keep_idx[r];
        const v4f* in  = (const v4f*)(Xs + ((size_t)(b * N_NODES + src)) * F_DIM);
        v4f*       out = (v4f*)(Xout + (size_t)r * F_DIM);
        __builtin_nontemporal_store(in[lane], out + lane);
    } else {
        int r = blockIdx.x - XBLKS;          // b*KEEP + i
        int b = r >> 11;
        int src = keep_idx[r];
        const float4* in = (const float4*)(As + ((size_t)(b * N_NODES + src)) * N_NODES);
        float4* rowv = (float4*)row;
        #pragma unroll
        for (int it = 0; it < 4; ++it) rowv[it * 256 + t] = in[it * 256 + t];
        __syncthreads();
        const int* idx = keep_idx + b * KEEP;
        float* outp = Aout + (size_t)r * KEEP;
        #pragma unroll
        for (int q = 0; q < 8; ++q) {
            int j = q * 256 + t;
            __builtin_nontemporal_store(row[idx[j]], outp + j);
        }
    }
}

extern "C" void kernel_launch(void* const* d_in, const int* in_sizes, int n_in,
                              void* d_out, int out_size, void* d_ws, size_t ws_size,
                              hipStream_t stream) {
    const float* Xs = (const float*)d_in[0];   // [4,4096,256]
    const float* As = (const float*)d_in[1];   // [4,4096,4096]
    const float* w  = (const float*)d_in[2];   // [256,1]

    float* out  = (float*)d_out;
    float* Xout = out;                                   // 4*2048*256
    float* Aout = out + (size_t)B_SZ * KEEP * F_DIM;     // 4*2048*2048
    unsigned* KV = (unsigned*)(Aout + (size_t)B_SZ * KEEP * KEEP);  // raw f32 bits

    char* ws = (char*)d_ws;
    double* xw       = (double*)ws;              // 128 KB
    double* logits   = (double*)(ws + 131072);   // 128 KB
    int*    keep_idx = (int*)(ws + 262144);      // 32 KB

    k_xw     <<<B_SZ * N_NODES / 4,      256, 0, stream>>>(Xs, w, xw);
    k_logits <<<B_SZ * N_NODES / LROWS,  256, 0, stream>>>(As, xw, logits);
    k_topk   <<<B_SZ,                   1024, 0, stream>>>(logits, keep_idx, KV);
    k_gather <<<XBLKS + B_SZ * KEEP,     256, 0, stream>>>(Xs, As, keep_idx, Xout, Aout);
}